// Round 8
// baseline (318.382 us; speedup 1.0000x reference)
//
#include <hip/hip_runtime.h>
#include <stdint.h>

// Problem constants (fixed by the reference)
#define CHARS   10000
#define KPAD    10240   // K padded to multiple of 64
#define HIDDEN  1024
#define OUTPUT  100
#define OPAD    128     // padded output cols for coalesced W2T
#define BATCH   4096
#define MAXLEN  2048
#define BK      32      // GEMM K-tile

typedef __bf16 bf16_t;
typedef __bf16 bf16x8 __attribute__((ext_vector_type(8)));
typedef __bf16 bf16x4 __attribute__((ext_vector_type(4)));
typedef float  f32x4  __attribute__((ext_vector_type(4)));
typedef uint32_t u32x4 __attribute__((ext_vector_type(4)));

// async global->LDS, 16B per lane; LDS dst = wave-uniform base + lane*16 (linear)
__device__ __forceinline__ void gload16(const bf16_t* g, bf16_t* l) {
    __builtin_amdgcn_global_load_lds(
        (__attribute__((address_space(1))) void*)const_cast<bf16_t*>(g),
        (__attribute__((address_space(3))) void*)l, 16, 0, 0);
}

// ---------------------------------------------------------------------------
// Legacy split prep (used only on the chunked fallback path)
// ---------------------------------------------------------------------------
__global__ void k_prep(const float* __restrict__ W1, bf16_t* __restrict__ W1b,
                       const float* __restrict__ W2, float* __restrict__ W2T,
                       const float* __restrict__ b1, float* __restrict__ hid) {
    const int bid = blockIdx.x, tid = threadIdx.x;
    if (bid < 2048) {
        const int N4 = (KPAD / 4) * HIDDEN;
        for (int i = bid * 256 + tid; i < N4; i += 2048 * 256) {
            int c4 = i % (KPAD / 4);
            int h  = i / (KPAD / 4);
            bf16x4 o;
            if (c4 * 4 < CHARS) {
                f32x4 v = *(const f32x4*)(W1 + (size_t)h * CHARS + (size_t)c4 * 4);
                o[0] = (bf16_t)v[0]; o[1] = (bf16_t)v[1];
                o[2] = (bf16_t)v[2]; o[3] = (bf16_t)v[3];
            } else {
                o[0] = o[1] = o[2] = o[3] = (bf16_t)0.0f;
            }
            *(bf16x4*)(W1b + (size_t)h * KPAD + (size_t)c4 * 4) = o;
        }
    } else if (bid < 2560) {
        int i = (bid - 2048) * 256 + tid;
        int o = i & (OPAD - 1), k = i >> 7;
        W2T[i] = (o < OUTPUT) ? W2[(size_t)o * HIDDEN + k] : 0.0f;
    } else {
        const int M4 = BATCH * HIDDEN / 4;
        for (int i = (bid - 2560) * 256 + tid; i < M4; i += 2048 * 256) {
            int h4 = i & (HIDDEN / 4 - 1);
            ((f32x4*)hid)[i] = ((const f32x4*)b1)[h4];
        }
    }
}

// ---------------------------------------------------------------------------
// Per-row histogram body (shared by both paths)
// ---------------------------------------------------------------------------
__device__ __forceinline__ void hist_body(uint32_t* h, const int* __restrict__ words,
                                          bf16_t* __restrict__ hist, int row,
                                          int dstRow, int tid) {
#pragma unroll
    for (int i = 0; i < KPAD / 4 / 256; ++i)  // 10 iters
        *(u32x4*)(h + (i * 256 + tid) * 4) = (u32x4){0u, 0u, 0u, 0u};
    __syncthreads();
    const int* w = words + (size_t)row * MAXLEN;
#pragma unroll
    for (int i = 0; i < MAXLEN / 4 / 256; ++i) {  // 2 iters
        int4 t4 = *(const int4*)(w + (i * 256 + tid) * 4);
        atomicAdd(&h[t4.x], 1u); atomicAdd(&h[t4.y], 1u);
        atomicAdd(&h[t4.z], 1u); atomicAdd(&h[t4.w], 1u);
    }
    __syncthreads();
    bf16_t* dst = hist + (size_t)dstRow * KPAD;
#pragma unroll
    for (int i = 0; i < KPAD / 8 / 256; ++i) {    // 5 iters
        int j = (i * 256 + tid) * 8;
        bf16x8 o;
#pragma unroll
        for (int q = 0; q < 8; ++q) o[q] = (bf16_t)(float)h[j + q];
        *(bf16x8*)(dst + j) = o;
    }
}

__global__ void k_hist(const int* __restrict__ words, bf16_t* __restrict__ hist,
                       int rowStart) {
    __shared__ uint32_t h[KPAD];              // 40 KB
    hist_body(h, words, hist, rowStart + blockIdx.x, blockIdx.x, threadIdx.x);
}

// ---------------------------------------------------------------------------
// Merged prep + hist (one dispatch):
//   blocks [0,4096)     : per-row histogram
//   blocks [4096,6144)  : W1 -> W1b bf16 conversion (grid-stride)
//   blocks [6144,6656)  : W2 -> W2T transpose
//   blocks [6656,8704)  : hid[b,h] = b1[h]  (only when initHid)
// ---------------------------------------------------------------------------
__global__ void k_preph(const int* __restrict__ words, bf16_t* __restrict__ hist,
                        const float* __restrict__ W1, bf16_t* __restrict__ W1b,
                        const float* __restrict__ W2, float* __restrict__ W2T,
                        const float* __restrict__ b1, float* __restrict__ hid,
                        int initHid) {
    __shared__ uint32_t h[KPAD];              // 40 KB (hist branch only)
    const int bid = blockIdx.x, tid = threadIdx.x;
    if (bid < BATCH) {
        hist_body(h, words, hist, bid, bid, tid);
    } else if (bid < BATCH + 2048) {
        const int b2i = bid - BATCH;
        const int N4 = (KPAD / 4) * HIDDEN;
        for (int i = b2i * 256 + tid; i < N4; i += 2048 * 256) {
            int c4 = i % (KPAD / 4);
            int hh = i / (KPAD / 4);
            bf16x4 o;
            if (c4 * 4 < CHARS) {
                f32x4 v = *(const f32x4*)(W1 + (size_t)hh * CHARS + (size_t)c4 * 4);
                o[0] = (bf16_t)v[0]; o[1] = (bf16_t)v[1];
                o[2] = (bf16_t)v[2]; o[3] = (bf16_t)v[3];
            } else {
                o[0] = o[1] = o[2] = o[3] = (bf16_t)0.0f;
            }
            *(bf16x4*)(W1b + (size_t)hh * KPAD + (size_t)c4 * 4) = o;
        }
    } else if (bid < BATCH + 2560) {
        int i = (bid - BATCH - 2048) * 256 + tid;
        int o = i & (OPAD - 1), k = i >> 7;
        W2T[i] = (o < OUTPUT) ? W2[(size_t)o * HIDDEN + k] : 0.0f;
    } else if (initHid) {
        const int b2i = bid - BATCH - 2560;
        const int M4 = BATCH * HIDDEN / 4;
        for (int i = b2i * 256 + tid; i < M4; i += 2048 * 256) {
            int h4 = i & (HIDDEN / 4 - 1);
            ((f32x4*)hid)[i] = ((const f32x4*)b1)[h4];
        }
    }
}

// ---------------------------------------------------------------------------
// 256x256x(BK=32) bf16 MFMA GEMM, 3-buffer free-flow schedule.
//   R8: R4-R6 proved the per-16-k lockstep (read-burst then MFMA-burst, all
//   waves barrier-synced, any fence flavor) serializes LDS+MFMA pipes
//   (1410 cy vs ~700 overlapped). Fix = widen the fence-free window:
//   3 LDS buffers (96 KB), stages target buf t+2 (never the buffer being
//   read or the next one) -> ONE barrier per K-tile, ZERO internal fences.
//   Per tile: {4 gload16 -> buf t+2 | 12 ds_read_b128 + 32 MFMA from buf t,
//   compiler-scheduled | vmcnt(4) | barrier}.
//   Ledger: buf t+2 was last read in tile t-1 (done at entry barrier) -> WAR
//   ok; vmcnt(4) at tile end = prev tile's 4 stages landed -> buf t+1 RAW ok;
//   2-tile lookahead (~2600cy) covers ~900cy HBM latency; tail clamps to
//   tile 0 (valid mem, dead buffer).
//   XOR swizzle at 16B granularity within 64B rows (slot ^= row&3), written
//   via inverse-swizzled global source (rule 21) -> uniform 8 dwords/bank.
//   EPI=1: split-K slices store to private slabs (k_red sums).  EPI=0: atomic.
// ---------------------------------------------------------------------------
template <int EPI>
__global__ void __launch_bounds__(512)
k_gemm(const bf16_t* __restrict__ A, const bf16_t* __restrict__ Bt,
       float* __restrict__ hid, float* __restrict__ extraSlabs,
       int KT, int mtiles) {
    __shared__ __attribute__((aligned(16))) bf16_t As[3][256 * BK];  // 48 KB
    __shared__ __attribute__((aligned(16))) bf16_t Bs[3][256 * BK];  // 48 KB

    // chunked XCD swizzle (grid % 8 == 0): same (n,s) group contiguous per XCD
    const int nblk = gridDim.x;
    int idx = blockIdx.x;
    if ((nblk & 7) == 0) idx = (idx & 7) * (nblk >> 3) + (idx >> 3);
    const int mt = idx % mtiles;
    const int ns = idx / mtiles;
    const int m0 = mt * 256;
    const int n0 = (ns & 3) * 256;        // HIDDEN/256 == 4
    const int kbeg = (ns >> 2) * KT;      // k-slice start, in BK-wide tiles

    const int tid  = threadIdx.x;
    const int lane = tid & 63;
    const int wave = tid >> 6;            // 0..7
    const int wm64 = (wave >> 2) * 64;    // wave row within 128-row quadrant
    const int wn32 = (wave & 3) * 32;     // wave col within 128-col quadrant
    const int l15  = lane & 15;
    const int hi   = lane >> 4;           // k-octet selector 0..3
    const int x2   = l15 & 3;             // read-side swizzle XOR (row&3)
    const int koff = ((hi ^ x2)) * 16;    // byte offset within 64B row

    int arow[4], brow[2];
#pragma unroll
    for (int fi = 0; fi < 4; ++fi) arow[fi] = (wm64 + fi * 16 + l15) * (BK * 2);
#pragma unroll
    for (int fj = 0; fj < 2; ++fj) brow[fj] = (wn32 + fj * 16 + l15) * (BK * 2);

    // staging map: lane -> row (lane>>2), 16B chunk (lane&3)^(row&3) [inverse
    // swizzle]; wave w covers rows [w*16, w*16+16) and [128+w*16, ...)
    const int srow = lane >> 2;
    const int csw8 = ((lane & 3) ^ (srow & 3)) * 8;
    const bf16_t* Ab = A  + (size_t)(m0 + wave * 16 + srow) * KPAD + csw8;
    const bf16_t* Bb = Bt + (size_t)(n0 + wave * 16 + srow) * KPAD + csw8;
    const int wso = wave * 512;           // LDS element offset of wave's slot

    f32x4 acc[2][2][4][2] = {};

#define STAGE4(DA, DB, KTILE_) do {                                            \
    int kte_ = (KTILE_); if (kte_ >= KT) kte_ = 0; /* tail clamp */            \
    const size_t kc_ = (size_t)(kbeg + kte_) * BK;                             \
    gload16(Ab + kc_,                        (DA) + wso);                      \
    gload16(Ab + (size_t)128 * KPAD + kc_,   (DA) + 4096 + wso);               \
    gload16(Bb + kc_,                        (DB) + wso);                      \
    gload16(Bb + (size_t)128 * KPAD + kc_,   (DB) + 4096 + wso);               \
} while (0)

#define LDA4(DST, BASE, QOFF) do {                                            \
    _Pragma("unroll") for (int fi = 0; fi < 4; ++fi)                          \
        DST[fi] = *(const bf16x8*)((const char*)(BASE) + (QOFF) +             \
                                   arow[fi] + koff);                          \
} while (0)

#define LDB2(DST, BASE, QOFF) do {                                            \
    _Pragma("unroll") for (int fj = 0; fj < 2; ++fj)                          \
        DST[fj] = *(const bf16x8*)((const char*)(BASE) + (QOFF) +             \
                                   brow[fj] + koff);                          \
} while (0)

#define MM8(QI, QJ, FA, FB) do {                                              \
    _Pragma("unroll") for (int fi = 0; fi < 4; ++fi)                          \
        _Pragma("unroll") for (int fj = 0; fj < 2; ++fj)                      \
            acc[QI][QJ][fi][fj] = __builtin_amdgcn_mfma_f32_16x16x32_bf16(    \
                FA[fi], FB[fj], acc[QI][QJ][fi][fj], 0, 0, 0);                \
} while (0)

// tile boundary: vmcnt then barrier, sched fences on both sides
#define TILEBAR() do {                                                        \
    asm volatile("s_waitcnt vmcnt(4)" ::: "memory");                          \
    __builtin_amdgcn_sched_barrier(0);                                        \
    __builtin_amdgcn_s_barrier();                                             \
    __builtin_amdgcn_sched_barrier(0);                                        \
} while (0)

    // rotating buffer pointers: rd = tile t, nx = t+1, st = t+2 (stage target)
    bf16_t *rdA = &As[0][0], *nxA = &As[1][0], *stA = &As[2][0];
    bf16_t *rdB = &Bs[0][0], *nxB = &Bs[1][0], *stB = &Bs[2][0];

    // prologue: stage tile0 -> buf0, tile1 -> buf1; vmcnt(4) => tile0 landed
    STAGE4(rdA, rdB, 0);
    STAGE4(nxA, nxB, 1);
    TILEBAR();

    for (int t = 0; t < KT; ++t) {
        STAGE4(stA, stB, t + 2);          // issue early; lands by end of t+1
        bf16x8 fa[4], ga[4], fb[2], gb[2];
        LDA4(fa, rdA, 0);                 // qi=0 rows
        LDB2(fb, rdB, 0);                 // qj=0 cols
        MM8(0, 0, fa, fb);
        LDA4(ga, rdA, 8192);              // qi=1 rows
        MM8(1, 0, ga, fb);
        LDB2(gb, rdB, 8192);              // qj=1 cols
        MM8(0, 1, fa, gb);
        MM8(1, 1, ga, gb);
        TILEBAR();
        bf16_t* tp;
        tp = rdA; rdA = nxA; nxA = stA; stA = tp;
        tp = rdB; rdB = nxB; nxB = stB; stB = tp;
    }
#undef TILEBAR
#undef MM8
#undef LDB2
#undef LDA4
#undef STAGE4

    // epilogue: C/D layout col=lane&15, row=(lane>>4)*4+reg  [guide §3, m89]
    const int er = hi * 4;
    float* dstBase;
    if (EPI == 1) {
        const int s = ns >> 2;            // split-K slice -> slab
        dstBase = (s == 0) ? hid : extraSlabs + (size_t)(s - 1) * BATCH * HIDDEN;
    } else {
        dstBase = hid;
    }
#pragma unroll
    for (int qi = 0; qi < 2; ++qi)
#pragma unroll
    for (int qj = 0; qj < 2; ++qj)
#pragma unroll
    for (int fi = 0; fi < 4; ++fi)
#pragma unroll
    for (int fj = 0; fj < 2; ++fj) {
        float* dst = dstBase + (size_t)(m0 + qi * 128 + wm64 + fi * 16 + er) * HIDDEN
                             + (n0 + qj * 128 + wn32 + fj * 16 + l15);
#pragma unroll
        for (int r = 0; r < 4; ++r) {
            if (EPI == 1) dst[(size_t)r * HIDDEN] = acc[qi][qj][fi][fj][r];
            else          atomicAdd(dst + (size_t)r * HIDDEN, acc[qi][qj][fi][fj][r]);
        }
    }
}

// ---------------------------------------------------------------------------
// hid = b1 + slab0(hid) + slab1 + slab2 + slab3   (in-place on slab0)
// ---------------------------------------------------------------------------
__global__ void k_red(float* __restrict__ hid, const float* __restrict__ extra,
                      const float* __restrict__ b1) {
    const int N4 = BATCH * HIDDEN / 4;    // 1,048,576 f32x4 groups
    const float* e0 = extra;
    const float* e1 = extra + (size_t)BATCH * HIDDEN;
    const float* e2 = extra + (size_t)2 * BATCH * HIDDEN;
    for (int i = blockIdx.x * 256 + threadIdx.x; i < N4; i += 2048 * 256) {
        int h4 = i & (HIDDEN / 4 - 1);
        f32x4 v = ((const f32x4*)hid)[i];
        v += ((const f32x4*)b1)[h4];
        v += ((const f32x4*)e0)[i];
        v += ((const f32x4*)e1)[i];
        v += ((const f32x4*)e2)[i];
        ((f32x4*)hid)[i] = v;
    }
}

// ---------------------------------------------------------------------------
// out[b,o] = sum_k hid[b,k] * W2T[k,o] + b2[o]
// ---------------------------------------------------------------------------
__global__ void k_out(const float* __restrict__ hid, const float* __restrict__ W2T,
                      const float* __restrict__ b2, float* __restrict__ out) {
    const int tid = threadIdx.x;
    const int o4  = (tid & 31) * 4;       // 0,4,...,124
    const int rs  = tid >> 5;             // 0..7
    const int row = blockIdx.x * 8 + rs;
    const float* hrow = hid + (size_t)row * HIDDEN;
    f32x4 acc = {0.f, 0.f, 0.f, 0.f};
    for (int k0 = 0; k0 < HIDDEN; k0 += 4) {
        f32x4 hv = *(const f32x4*)(hrow + k0);
#pragma unroll
        for (int q = 0; q < 4; ++q) {
            f32x4 wv = *(const f32x4*)(W2T + (size_t)(k0 + q) * OPAD + o4);
            acc += hv[q] * wv;
        }
    }
    if (o4 < OUTPUT) {
        float* op = out + (size_t)row * OUTPUT + o4;
#pragma unroll
        for (int q = 0; q < 4; ++q)
            op[q] = acc[q] + b2[o4 + q];
    }
}

// ---------------------------------------------------------------------------
// split-K: largest S with grid = mtiles*4*S <= 256 (1 block/CU at 96KB LDS);
// all candidates divide 320 (total BK=32 tiles).
// ---------------------------------------------------------------------------
static inline int pick_S(int mtiles) {
    const int cands[10] = {80, 40, 20, 16, 10, 8, 5, 4, 2, 1};
    for (int i = 0; i < 10; ++i)
        if (mtiles * 4 * cands[i] <= 256) return cands[i];
    return 1;
}

extern "C" void kernel_launch(void* const* d_in, const int* in_sizes, int n_in,
                              void* d_out, int out_size, void* d_ws, size_t ws_size,
                              hipStream_t stream) {
    (void)in_sizes; (void)n_in; (void)out_size;
    const int*   words = (const int*)d_in[0];
    const float* W1    = (const float*)d_in[1];
    const float* b1    = (const float*)d_in[2];
    const float* W2    = (const float*)d_in[3];
    const float* b2    = (const float*)d_in[4];
    float* out = (float*)d_out;

    // workspace layout
    char* ws = (char*)d_ws;
    size_t off = 0;
    bf16_t* W1b  = (bf16_t*)(ws + off); off += (size_t)HIDDEN * KPAD * sizeof(bf16_t); // 21.0 MB
    float*  hid  = (float*) (ws + off); off += (size_t)BATCH * HIDDEN * sizeof(float); // 16.8 MB
    float*  W2T  = (float*) (ws + off); off += (size_t)HIDDEN * OPAD * sizeof(float);  // 0.5 MB
    const size_t slabBytes = (size_t)BATCH * HIDDEN * sizeof(float);                   // 16.8 MB
    const size_t histBytes = (size_t)BATCH * KPAD * sizeof(bf16_t);                    // 83.9 MB

    if (ws_size >= off + 3 * slabBytes + histBytes) {
        // slab path: store-based split-K epilogue + reduce kernel
        float* extra = (float*)(ws + off);
        bf16_t* histC = (bf16_t*)(ws + off + 3 * slabBytes);
        k_preph<<<dim3(BATCH + 4608), dim3(256), 0, stream>>>(
            words, histC, W1, W1b, W2, W2T, b1, hid, 0);
        int mtiles = BATCH / 256;                 // 16
        int S = 4;
        int KT = (KPAD / BK) / S;                 // 80
        k_gemm<1><<<dim3(mtiles * 4 * S), dim3(512), 0, stream>>>(
            histC, W1b, hid, extra, KT, mtiles);
        k_red<<<dim3(2048), dim3(256), 0, stream>>>(hid, extra, b1);
    } else {
        bf16_t* histC = (bf16_t*)(ws + off);
        size_t rem = (ws_size > off) ? (ws_size - off) : 0;
        int chunkRows = (int)(rem / ((size_t)KPAD * sizeof(bf16_t)));
        chunkRows = (chunkRows / 256) * 256;
        if (chunkRows > BATCH) chunkRows = BATCH;
        if (chunkRows < 256)   chunkRows = 256;

        if (chunkRows >= BATCH) {
            // full-batch atomic path
            k_preph<<<dim3(BATCH + 4608), dim3(256), 0, stream>>>(
                words, histC, W1, W1b, W2, W2T, b1, hid, 1);
            int mtiles = BATCH / 256;
            int S = pick_S(mtiles);
            int KT = (KPAD / BK) / S;
            k_gemm<0><<<dim3(mtiles * 4 * S), dim3(512), 0, stream>>>(
                histC, W1b, hid, nullptr, KT, mtiles);
        } else {
            // chunked fallback (small workspace)
            k_prep<<<dim3(4608), dim3(256), 0, stream>>>(W1, W1b, W2, W2T, b1, hid);
            for (int r0 = 0; r0 < BATCH; r0 += chunkRows) {
                int rows = BATCH - r0;
                if (rows > chunkRows) rows = chunkRows;
                k_hist<<<dim3(rows), dim3(256), 0, stream>>>(words, histC, r0);
                int mtiles = rows / 256;
                int S = pick_S(mtiles);
                int KT = (KPAD / BK) / S;
                k_gemm<0><<<dim3(mtiles * 4 * S), dim3(512), 0, stream>>>(
                    histC, W1b, hid + (size_t)r0 * HIDDEN, nullptr, KT, mtiles);
            }
        }
    }

    k_out<<<dim3(BATCH / 8), dim3(256), 0, stream>>>(hid, W2T, b2, out);
}